// Round 1
// baseline (351.465 us; speedup 1.0000x reference)
//
#include <hip/hip_runtime.h>

// A=500 atoms, R=14 reps, n_ao=5800, out=[A,A,R,R]=49M f32 (196 MB).
// Scatter is collision-free; out tile (a1,a2) = row/col-permuted copy of a
// contiguous feat submatrix, zero-filled at empty rep slots.
// v2: software-pipelined (reg-staged prefetch of super s+1 overlaps emit of s),
// double-buffered LDS, 1 barrier/super instead of 2, super-invariant emit
// decode hoisted, WP 360->356 (8-row LDS bank period).
constexpr int R = 14;
constexpr int A = 500;
constexpr int TOTAL = A * R;          // 7000
constexpr int TILE = R * R;           // 196
constexpr int G = 25;                 // a2 atoms per sub-tile
constexpr int NG = A / G;             // 20
constexpr int SUPER = 4;              // g-groups per block
constexpr int NSUP = NG / SUPER;      // 5
constexpr int WP = 356;               // LDS row stride (floats), %32=4 -> 8-row bank period
constexpr int CHUNK = G * TILE;       // 4900 floats per sub-tile

// ---- fused setup: one block, three phases (unchanged, known-good) --------
__global__ __launch_bounds__(1024) void setup_kernel(
        const int* __restrict__ dst, int n_ao,
        int* __restrict__ inv, int* __restrict__ arow,
        int* __restrict__ ncols, int* __restrict__ pm) {
    int tid = threadIdx.x;
    for (int t = tid; t < TOTAL; t += 1024) inv[t] = -1;
    __syncthreads();
    for (int t = tid; t < n_ao; t += 1024) inv[dst[t]] = t;  // collision-free
    __syncthreads();
    if (tid < A) {
        int a = tid, lo = 0x7fffffff, hi = -1;
#pragma unroll
        for (int r = 0; r < R; ++r) {
            int v = inv[a * R + r];
            if (v >= 0) { lo = min(lo, v); hi = max(hi, v); }
        }
        arow[a] = lo;
        ncols[a] = hi - lo + 1;
#pragma unroll
        for (int r = 0; r < R; ++r) {
            int v = inv[a * R + r];
            pm[a * R + r] = (v >= 0) ? (v - lo) : -1;
        }
    }
}

// ---- main: 2500 blocks x 512 threads; block = (a1, 4 g-groups) -----------
__global__ __launch_bounds__(512, 6) void tile_kernel(
        const float* __restrict__ feat,
        const int* __restrict__ arow,
        const int* __restrict__ ncols,
        const int* __restrict__ pm,
        float* __restrict__ out, int n_ao) {
    const int gs  = blockIdx.x % NSUP;
    const int a1  = blockIdx.x / NSUP;
    const int tid = threadIdx.x;

    __shared__ float buf[2][R][WP];       // double-buffered stage tile
    __shared__ int s_pr[R];
    __shared__ int s_pc[SUPER][G * R];
    __shared__ int s_off[SUPER][G];
    __shared__ int s_colA[SUPER];
    __shared__ int s_W4[SUPER];

    const int arow1 = arow[a1];
    const int n1    = ncols[a1];
    const int gbase = gs * (SUPER * G);   // first a2 atom of this block

    // ---- all per-super tables once, up front ----
    if (tid < R) s_pr[tid] = pm[a1 * R + tid];
    for (int t = tid; t < SUPER * G * R; t += 512)
        (&s_pc[0][0])[t] = pm[gbase * R + t];          // contiguous copy
    if (tid < SUPER) {
        const int g0 = gbase + tid * G;
        const int colA = arow[g0] & ~3;                // 16B align
        s_colA[tid] = colA;
        s_W4[tid]   = (arow[g0 + G - 1] + ncols[g0 + G - 1] - colA + 3) >> 2;
    }
    if (tid < SUPER * G) {
        const int sI = tid / G, i = tid - sI * G;
        const int g0 = gbase + sI * G;
        s_off[sI][i] = arow[g0 + i] - (arow[g0] & ~3);
    }
    __syncthreads();

    // ---- per-thread emit decode, computed ONCE (super-invariant) ----
    int a2i_[3], dk_[3][4], ci_[3][4];
    bool val_[3];
#pragma unroll
    for (int j = 0; j < 3; ++j) {
        const int o4 = tid * 4 + j * 2048;
        val_[j] = (o4 < CHUNK);
        const int o = val_[j] ? o4 : 0;
        int a2i = o / TILE;               // magic mul
        int e   = o - a2i * TILE;
        int r1  = e / R;                  // magic mul
        int r2  = e - r1 * R;
        a2i_[j] = a2i;
#pragma unroll
        for (int k = 0; k < 4; ++k) {
            dk_[j][k] = s_pr[r1];         // permuted LDS row (or -1)
            ci_[j][k] = a2i * R + r2;     // index into s_pc[s]
            if (++r2 == R) { r2 = 0; ++r1; }
        }
    }

    const int d0  = tid >> 7;             // 0..3: row phase
    const int c4  = tid & 127;            // float4 column slot
    const int rs4 = n_ao >> 2;
    const float4* feat4 = reinterpret_cast<const float4*>(feat);

    float4 rg[4];                         // reg staging (rows d0, d0+4, d0+8, d0+12)

    auto stage_load = [&](int s) {
        const int W4 = s_W4[s];
        if (c4 < W4) {
            const float4* src = feat4 + (long long)arow1 * rs4 + (s_colA[s] >> 2) + c4;
#pragma unroll
            for (int u = 0; u < 4; ++u) {
                const int d = d0 + u * 4;
                if (d < n1) rg[u] = src[(long long)d * rs4];
            }
        }
    };
    auto stage_write = [&](int nb, int s) {
        const int W4 = s_W4[s];
        if (c4 < W4) {
#pragma unroll
            for (int u = 0; u < 4; ++u) {
                const int d = d0 + u * 4;
                if (d < n1)
                    *reinterpret_cast<float4*>(&buf[nb][d][c4 << 2]) = rg[u];
            }
        }
    };

    // prologue: stage super 0 into buf[0]
    stage_load(0);
    stage_write(0, 0);
    __syncthreads();

    int cb = 0;
    for (int s = 0; s < SUPER; ++s) {
        // issue next super's HBM loads; they fly underneath the emit below
        if (s + 1 < SUPER) stage_load(s + 1);

        // emit super s from buf[cb]: 4900 consecutive floats, float4 stores
        const long long outbase =
            ((long long)a1 * A + gbase + s * G) * (long long)TILE;
        const int* pcS = &s_pc[s][0];
#pragma unroll
        for (int j = 0; j < 3; ++j) {
            if (!val_[j]) continue;       // only j=2 is partial (tid<201)
            const int off = s_off[s][a2i_[j]];
            float4 v;
            float* vp = &v.x;
#pragma unroll
            for (int k = 0; k < 4; ++k) {
                const int d = dk_[j][k];
                const int c = pcS[ci_[j][k]];
                vp[k] = ((d | c) >= 0) ? buf[cb][d][off + c] : 0.0f;
            }
            *reinterpret_cast<float4*>(out + outbase + tid * 4 + j * 2048) = v;
        }

        if (s + 1 < SUPER) {
            stage_write(cb ^ 1, s + 1);   // compiler inserts minimal vmcnt wait here
            __syncthreads();              // single barrier per super
            cb ^= 1;
        }
    }
}

extern "C" void kernel_launch(void* const* d_in, const int* in_sizes, int n_in,
                              void* d_out, int out_size, void* d_ws, size_t ws_size,
                              hipStream_t stream) {
    const float* feat = (const float*)d_in[0];
    const int*   dst  = (const int*)d_in[1];
    int n_ao = in_sizes[1];              // 5800

    int* inv   = (int*)d_ws;             // 7000
    int* arow  = inv + TOTAL;            // 500
    int* ncols = arow + A;               // 500
    int* pm    = ncols + A;              // 7000

    setup_kernel<<<1, 1024, 0, stream>>>(dst, n_ao, inv, arow, ncols, pm);
    tile_kernel<<<A * NSUP, 512, 0, stream>>>(feat, arow, ncols, pm,
                                              (float*)d_out, n_ao);
}